// Round 4
// baseline (1219.269 us; speedup 1.0000x reference)
//
#include <hip/hip_runtime.h>

typedef unsigned short u16;
typedef __attribute__((ext_vector_type(8))) __bf16 bf16x8;
typedef __attribute__((ext_vector_type(4))) float f32x4;

__device__ __forceinline__ u16 f2bf(float f) {
  union { float f; unsigned u; } v; v.f = f;
  unsigned r = v.u + 0x7fffu + ((v.u >> 16) & 1u);
  return (u16)(r >> 16);
}

__device__ __forceinline__ void gld16(const void* g, const void* l) {
  __builtin_amdgcn_global_load_lds((const __attribute__((address_space(1))) void*)g,
                                   (__attribute__((address_space(3))) void*)l, 16, 0, 0);
}

// raw barrier (no vmcnt drain) + compiler memory fences
#define BARX() do { asm volatile("" ::: "memory"); __builtin_amdgcn_s_barrier(); \
                    asm volatile("" ::: "memory"); } while (0)
// ds-read drain + scheduler fence (rule #18)
#define LGKM0() do { asm volatile("s_waitcnt lgkmcnt(0)" ::: "memory"); \
                     __builtin_amdgcn_sched_barrier(0); } while (0)
#define VMC(n) do { asm volatile("s_waitcnt vmcnt(" #n ")" ::: "memory"); \
                    __builtin_amdgcn_sched_barrier(0); } while (0)

// ---------------- merged small prep ----------------
__global__ __launch_bounds__(256) void k_prep_small(
    const float* w1, const float* rw,
    const float* g1, const float* b1, const float* m1, const float* v1,
    const float* g2, const float* b2, const float* m2, const float* v2,
    u16* w1b, u16* cwt,
    float* scale1, float* shift1, float* scale2, float* shift2, float* cbf)
{
  int i = blockIdx.x * 256 + threadIdx.x;
  if (i < 32768) { w1b[i] = f2bf(w1[i]); return; }
  i -= 32768;
  if (i < 655360) {
    int n = i >> 10, c = i & 1023;
    cwt[i] = (n < 600) ? f2bf(rw[n * 1025 + c]) : (u16)0;
    return;
  }
  i -= 655360;
  if (i < 64) {
    float s = g1[i] * rsqrtf(v1[i] + 1e-5f);
    scale1[i] = s; shift1[i] = b1[i] - m1[i] * s;
  } else if (i < 1088) {
    int c = i - 64;
    float s = g2[c] * rsqrtf(v2[c] + 1e-5f);
    scale2[c] = s; shift2[c] = b2[c] - m2[c] * s;
  } else if (i < 1728) {
    int n = i - 1088;
    cbf[n] = (n < 600) ? rw[n * 1025 + 1024] : 0.f;
  }
}

// w2 (1024,1280,3,3) OIHW -> w2t[dy][o][dx*1280+ci] bf16
__global__ __launch_bounds__(256) void k_prep_w2(const float* w2, u16* w2t) {
  __shared__ float buf[11520];
  int o = blockIdx.x;
  const float* src = w2 + (size_t)o * 11520;
  for (int i = threadIdx.x; i < 11520; i += 256) buf[i] = src[i];
  __syncthreads();
  for (int t = 0; t < 9; ++t) {
    int dy = t / 3, dx = t - dy * 3;
    u16* dst = w2t + ((size_t)dy * 1024 + o) * 3840 + dx * 1280;
    for (int ci = threadIdx.x; ci < 1280; ci += 256) dst[ci] = f2bf(buf[ci * 9 + t]);
  }
}

// feat0 NCHW (64,1024,19,19) -> cat[b][1+h][1+w][256+c] bf16 (NHWC, padded 21x21)
__global__ __launch_bounds__(256) void k_feat0(const float* feat0, u16* cat) {
  __shared__ float tile[32][33];
  int b = blockIdx.z, c0 = blockIdx.y * 32, p0 = blockIdx.x * 32;
  int tid = threadIdx.x;
  int lo = tid & 31, hi = tid >> 5;
#pragma unroll
  for (int pass = 0; pass < 4; ++pass) {
    int cl = pass * 8 + hi;
    int p = p0 + lo;
    tile[cl][lo] = (p < 361) ? feat0[((size_t)(b * 1024 + c0 + cl)) * 361 + p] : 0.f;
  }
  __syncthreads();
#pragma unroll
  for (int pass = 0; pass < 4; ++pass) {
    int pl = pass * 8 + hi;
    int p = p0 + pl;
    if (p < 361) {
      int h = p / 19, w = p - h * 19;
      cat[(((size_t)b * 21 + 1 + h) * 21 + 1 + w) * 1280 + 256 + c0 + lo] = f2bf(tile[lo][pl]);
    }
  }
}

// ---------------- conv1 (1x1, 512->64) + BN + leaky + reorg -> cat ch 0..255 ----------------
__global__ __launch_bounds__(256) void k_conv1(const float* feat1, const u16* w1b,
    const float* scale1, const float* shift1, u16* cat)
{
  __shared__ u16 As[128 * 40];
  __shared__ u16 Bs[64 * 32];
  int tid = threadIdx.x;
  int wave = tid >> 6, lane = tid & 63;
  int wr = wave >> 1, wc = wave & 1;
  int lm = lane & 15, lq = lane >> 4;
  int csw = (lq ^ ((lm >> 1) & 3)) * 8;   // swizzled read chunk (u16 units)
  int m0 = blockIdx.x * 128;

  int mLoc = tid & 127, cHalf = tid >> 7;
  int mA = m0 + mLoc;
  int bA = mA / 1444, qA = mA - bA * 1444;
  const float* aG = feat1 + ((size_t)bA * 512) * 1444 + qA;

  const u16* bG = w1b + (tid >> 2) * 512 + (((tid & 3) ^ ((tid >> 3) & 3)) * 8);
  char* BsW = (char*)Bs + wave * 1024;

  f32x4 acc[4][2];
#pragma unroll
  for (int i = 0; i < 4; ++i)
#pragma unroll
    for (int j = 0; j < 2; ++j)
#pragma unroll
      for (int r = 0; r < 4; ++r) acc[i][j][r] = 0.f;

  for (int k0 = 0; k0 < 512; k0 += 32) {
    gld16(bG + k0, BsW);
#pragma unroll
    for (int pass = 0; pass < 16; ++pass) {
      int c = pass * 2 + cHalf;
      As[mLoc * 40 + c] = f2bf(aG[(size_t)(k0 + c) * 1444]);
    }
    __syncthreads();
    bf16x8 aF[4], bF[2];
#pragma unroll
    for (int i = 0; i < 4; ++i)
      aF[i] = *(const bf16x8*)(As + (wr * 64 + i * 16 + lm) * 40 + lq * 8);
#pragma unroll
    for (int j = 0; j < 2; ++j)
      bF[j] = *(const bf16x8*)(Bs + (wc * 32 + j * 16 + lm) * 32 + csw);
#pragma unroll
    for (int i = 0; i < 4; ++i)
#pragma unroll
      for (int j = 0; j < 2; ++j)
        acc[i][j] = __builtin_amdgcn_mfma_f32_16x16x32_bf16(aF[i], bF[j], acc[i][j], 0, 0, 0);
    __syncthreads();
  }

  int o0 = wc * 32;
  float sc[2], sh[2];
#pragma unroll
  for (int j = 0; j < 2; ++j) {
    int o = o0 + j * 16 + lm;
    sc[j] = scale1[o]; sh[j] = shift1[o];
  }
#pragma unroll
  for (int i = 0; i < 4; ++i) {
#pragma unroll
    for (int r = 0; r < 4; ++r) {
      int m = m0 + wr * 64 + i * 16 + lq * 4 + r;
      int b = m / 1444, q = m - b * 1444;
      int yy = q / 38, xx = q - yy * 38;
      size_t base = (((size_t)b * 21 + 1 + (yy >> 1)) * 21 + 1 + (xx >> 1)) * 1280
                  + ((yy & 1) * 2 + (xx & 1)) * 64;
#pragma unroll
      for (int j = 0; j < 2; ++j) {
        float v = acc[i][j][r] * sc[j] + sh[j];
        v = v > 0.f ? v : 0.1f * v;
        cat[base + o0 + j * 16 + lm] = f2bf(v);
      }
    }
  }
}

// ---------------- conv2 (3x3, 1280->1024) + BN + leaky -> pre[m][1024] bf16 ----------------
// Faithful m201-geometry port: BM=BN=256, BK=64, 512 thr, 8 waves (2M x 4N),
// per-wave 128x64 -> 16 MFMA per phase (the proven cluster size). LDS 128 KiB dbuf.
// 4 phases/K-tile (one C-quadrant each): {ds_read subtile | stage | BAR | lgkm0 |
// setprio 16xMFMA | [counted vmcnt] | BAR}. Stage placement (retirement-verified):
//   p2: A-early rows {0-63,128-191} of kt+2 (read in p1, retired at p1-end)
//   p3: B rows 0-127 of kt+2           (B fully retired at p2-end)
//   p4: A-late {64-127,192-255} + B rows 128-255
// vmcnt ledger (8 issues/tile, in-order completion): p2-end vmcnt(12) guards p3's
// A-late; p4-end vmcnt(8) guards next tile's p1 (worst pos = B-late). Drain only kt>=178.
// Swizzle: chunk' = chunk ^ ((row>>1)&7) -> each ks-read spans all 32 banks.
__global__ __launch_bounds__(512, 2) void k_conv2(const u16* cat, const u16* w2t,
    const float* scale2, const float* shift2, u16* pre)
{
  __shared__ __align__(16) u16 As[2][16384];   // 256 rows x 64 u16 per buf
  __shared__ __align__(16) u16 Bs[2][16384];

  const int tid = threadIdx.x;
  const int wave = tid >> 6, lane = tid & 63;
  const int wr = wave >> 2, wc = wave & 3;     // 2M x 4N
  const int lm = lane & 15, lq = lane >> 4;
  const int m0 = (blockIdx.x >> 2) * 256;
  const int n0 = (blockIdx.x & 3) * 256;

  // staging: thread t -> row q*64 + (t>>3), chunk t&7; source inverse-swizzled
  const int rsub = tid >> 3;                   // 0..63
  const int cOff = ((tid & 7) ^ ((tid >> 4) & 7)) * 8;
  const int ldsT = rsub * 64 + (tid & 7) * 8;  // linear gld_lds dest (u16)

  const u16* aBase[4];
#pragma unroll
  for (int q = 0; q < 4; ++q) {
    int m = m0 + q * 64 + rsub; if (m > 23103) m = 23103;
    int b = m / 361, pq = m - b * 361, y = pq / 19, x = pq - y * 19;
    aBase[q] = cat + ((size_t)(b * 21 + y) * 21 + x) * 1280 + cOff;
  }
  const u16* bBase[4];
#pragma unroll
  for (int q = 0; q < 4; ++q)
    bBase[q] = w2t + (size_t)(n0 + q * 64 + rsub) * 3840 + cOff;

  // read-side swizzled chunk offsets for ks=0,1
  int ck[2];
#pragma unroll
  for (int ks = 0; ks < 2; ++ks) ck[ks] = ((ks * 4 + lq) ^ ((lm >> 1) & 7)) * 8;

  f32x4 acc[8][4];
#pragma unroll
  for (int i = 0; i < 8; ++i)
#pragma unroll
    for (int j = 0; j < 4; ++j)
#pragma unroll
      for (int r = 0; r < 4; ++r) acc[i][j][r] = 0.f;

  // A: part0 -> LDS rows {0-63,128-191} (q=0,2); part1 -> {64-127,192-255} (q=1,3)
  auto stA = [&](int p, int part, int off) {
#pragma unroll
    for (int s = 0; s < 2; ++s) {
      int q = s * 2 + part;
      gld16(aBase[q] + off, &As[p][q * 4096 + ldsT]);
    }
  };
  // B: g=0 -> rows 0-127 (q=0,1); g=1 -> rows 128-255 (q=2,3)
  auto stB = [&](int p, int g, int off) {
#pragma unroll
    for (int s = 0; s < 2; ++s) {
      int q = g * 2 + s;
      gld16(bBase[q] + off, &Bs[p][q * 4096 + ldsT]);
    }
  };

  // prologue: tiles 0,1 staged in ledger order (A-e, B-lo, A-l, B-hi)
  stA(0, 0, 0);  stB(0, 0, 0);  stA(0, 1, 0);  stB(0, 1, 0);
  stA(1, 0, 64); stB(1, 0, 64); stA(1, 1, 64); stB(1, 1, 64);
  VMC(8);            // tile0 fully landed (8 newest = tile1)
  BARX();

  int dyS = 0, koS = 128;   // K-state for tile kt+2

  for (int kt = 0; kt < 180; ++kt) {
    const int p = kt & 1;
    const bool pf = (kt < 178);
    const int offA = dyS * 26880 + koS;
    const int offB = dyS * 3932160 + koS;
    const u16* Ap = &As[p][(wr * 128 + lm) * 64];
    const u16* Bp = &Bs[p][(wc * 64 + lm) * 64];

    bf16x8 aF[4][2], bF[4][2];

    // ---- phase 1: read A-early (8) + B j0,j1 (4); MFMA quad (i0-3, j0-1) ----
#pragma unroll
    for (int i = 0; i < 4; ++i)
#pragma unroll
      for (int ks = 0; ks < 2; ++ks)
        aF[i][ks] = *(const bf16x8*)(Ap + i * 1024 + ck[ks]);
#pragma unroll
    for (int j = 0; j < 2; ++j)
#pragma unroll
      for (int ks = 0; ks < 2; ++ks)
        bF[j][ks] = *(const bf16x8*)(Bp + j * 1024 + ck[ks]);
    BARX();
    LGKM0();
    __builtin_amdgcn_s_setprio(1);
#pragma unroll
    for (int ks = 0; ks < 2; ++ks)
#pragma unroll
      for (int i = 0; i < 4; ++i)
#pragma unroll
        for (int j = 0; j < 2; ++j)
          acc[i][j] = __builtin_amdgcn_mfma_f32_16x16x32_bf16(aF[i][ks], bF[j][ks], acc[i][j], 0, 0, 0);
    __builtin_amdgcn_s_setprio(0);
    BARX();

    // ---- phase 2: read B j2,j3 (4); stage A-early(kt+2); MFMA (i0-3, j2-3) ----
#pragma unroll
    for (int j = 2; j < 4; ++j)
#pragma unroll
      for (int ks = 0; ks < 2; ++ks)
        bF[j][ks] = *(const bf16x8*)(Bp + j * 1024 + ck[ks]);
    if (pf) stA(p, 0, offA);
    BARX();
    LGKM0();
    __builtin_amdgcn_s_setprio(1);
#pragma unroll
    for (int ks = 0; ks < 2; ++ks)
#pragma unroll
      for (int i = 0; i < 4; ++i)
#pragma unroll
        for (int j = 2; j < 4; ++j)
          acc[i][j] = __builtin_amdgcn_mfma_f32_16x16x32_bf16(aF[i][ks], bF[j][ks], acc[i][j], 0, 0, 0);
    __builtin_amdgcn_s_setprio(0);
    if (pf) { VMC(12); } else { VMC(0); }
    BARX();

    // ---- phase 3: read A-late (8); stage B-lo(kt+2); MFMA (i4-7, j2-3) ----
#pragma unroll
    for (int i = 0; i < 4; ++i)
#pragma unroll
      for (int ks = 0; ks < 2; ++ks)
        aF[i][ks] = *(const bf16x8*)(Ap + 4096 + i * 1024 + ck[ks]);
    if (pf) stB(p, 0, offB);
    BARX();
    LGKM0();
    __builtin_amdgcn_s_setprio(1);
#pragma unroll
    for (int ks = 0; ks < 2; ++ks)
#pragma unroll
      for (int i = 0; i < 4; ++i)
#pragma unroll
        for (int j = 2; j < 4; ++j)
          acc[4 + i][j] = __builtin_amdgcn_mfma_f32_16x16x32_bf16(aF[i][ks], bF[j][ks], acc[4 + i][j], 0, 0, 0);
    __builtin_amdgcn_s_setprio(0);
    BARX();

    // ---- phase 4: no reads; stage A-late + B-hi(kt+2); MFMA (i4-7, j0-1) ----
    if (pf) { stA(p, 1, offA); stB(p, 1, offB); }
    __builtin_amdgcn_s_setprio(1);
#pragma unroll
    for (int ks = 0; ks < 2; ++ks)
#pragma unroll
      for (int i = 0; i < 4; ++i)
#pragma unroll
        for (int j = 0; j < 2; ++j)
          acc[4 + i][j] = __builtin_amdgcn_mfma_f32_16x16x32_bf16(aF[i][ks], bF[j][ks], acc[4 + i][j], 0, 0, 0);
    __builtin_amdgcn_s_setprio(0);
    if (pf) { VMC(8); } else { VMC(0); }
    BARX();

    koS += 64; if (koS == 3840) { koS = 0; ++dyS; }
  }

  // ---- epilogue: BN + leaky -> pre ----
  int nn[4]; float sc[4], sh[4];
#pragma unroll
  for (int j = 0; j < 4; ++j) {
    nn[j] = n0 + wc * 64 + j * 16 + lm;
    sc[j] = scale2[nn[j]]; sh[j] = shift2[nn[j]];
  }
#pragma unroll
  for (int i = 0; i < 8; ++i) {
#pragma unroll
    for (int r = 0; r < 4; ++r) {
      int m = m0 + wr * 128 + i * 16 + lq * 4 + r;
      if (m < 23104) {
        u16* row = pre + (size_t)m * 1024;
#pragma unroll
        for (int j = 0; j < 4; ++j) {
          float v = acc[i][j][r] * sc[j] + sh[j];
          v = v > 0.f ? v : 0.1f * v;
          row[nn[j]] = f2bf(v);
        }
      }
    }
  }
}

// ---------------- einsum: det[cw=600][pix=23104]; A=cwt(640x1024), B=pre(23104x1024) ----
__global__ __launch_bounds__(256) void k_einsum(const u16* pre, const u16* cwt,
    const float* cbf, float* out)
{
  __shared__ u16 As[4096];
  __shared__ u16 Bs[4096];
  int tid = threadIdx.x;
  int wave = tid >> 6, lane = tid & 63;
  int wr = wave >> 1, wc = wave & 1;
  int lm = lane & 15, lq = lane >> 4;
  int csw = (lq ^ ((lm >> 1) & 3)) * 8;
  int m0 = blockIdx.x * 128;
  int n0 = blockIdx.y * 128;

  int r0 = tid >> 2;
  int seg = (((tid & 3) ^ ((tid >> 3) & 3)) * 8);
  const u16* aP0 = cwt + (size_t)(m0 + r0) * 1024 + seg;
  const u16* aP1 = aP0 + (size_t)64 * 1024;
  int q0 = n0 + r0;       if (q0 > 23103) q0 = 23103;
  int q1 = n0 + r0 + 64;  if (q1 > 23103) q1 = 23103;
  const u16* bP0 = pre + (size_t)q0 * 1024 + seg;
  const u16* bP1 = pre + (size_t)q1 * 1024 + seg;

  char* AsW = (char*)As + wave * 1024;
  char* BsW = (char*)Bs + wave * 1024;

  f32x4 acc[4][4];
#pragma unroll
  for (int i = 0; i < 4; ++i)
#pragma unroll
    for (int j = 0; j < 4; ++j)
#pragma unroll
      for (int r = 0; r < 4; ++r) acc[i][j][r] = 0.f;

  for (int k0 = 0; k0 < 1024; k0 += 32) {
    gld16(aP0 + k0, AsW);
    gld16(aP1 + k0, AsW + 4096);
    gld16(bP0 + k0, BsW);
    gld16(bP1 + k0, BsW + 4096);
    __syncthreads();
    bf16x8 aF[4], bF[4];
#pragma unroll
    for (int i = 0; i < 4; ++i)
      aF[i] = *(const bf16x8*)(As + (wr * 64 + i * 16 + lm) * 32 + csw);
#pragma unroll
    for (int j = 0; j < 4; ++j)
      bF[j] = *(const bf16x8*)(Bs + (wc * 64 + j * 16 + lm) * 32 + csw);
#pragma unroll
    for (int i = 0; i < 4; ++i)
#pragma unroll
      for (int j = 0; j < 4; ++j)
        acc[i][j] = __builtin_amdgcn_mfma_f32_16x16x32_bf16(aF[i], bF[j], acc[i][j], 0, 0, 0);
    __syncthreads();
  }

  int pix[4], pb[4], pp[4];
#pragma unroll
  for (int j = 0; j < 4; ++j) {
    pix[j] = n0 + wc * 64 + j * 16 + lm;
    int b = pix[j] / 361;
    pb[j] = b; pp[j] = pix[j] - b * 361;
  }
#pragma unroll
  for (int i = 0; i < 4; ++i) {
#pragma unroll
    for (int r = 0; r < 4; ++r) {
      int cw = m0 + wr * 64 + i * 16 + lq * 4 + r;
      if (cw < 600) {
        float bias = cbf[cw];
#pragma unroll
        for (int j = 0; j < 4; ++j) {
          if (pix[j] < 23104)
            out[(size_t)pb[j] * 216600 + (size_t)cw * 361 + pp[j]] = acc[i][j][r] + bias;
        }
      }
    }
  }
}

// ---------------- launch ----------------

extern "C" void kernel_launch(void* const* d_in, const int* in_sizes, int n_in,
                              void* d_out, int out_size, void* d_ws, size_t ws_size,
                              hipStream_t stream) {
  const float* feat0 = (const float*)d_in[0];
  const float* feat1 = (const float*)d_in[1];
  const float* w1 = (const float*)d_in[2];
  const float* g1 = (const float*)d_in[3];
  const float* b1 = (const float*)d_in[4];
  const float* m1 = (const float*)d_in[5];
  const float* v1 = (const float*)d_in[6];
  const float* w2 = (const float*)d_in[7];
  const float* g2 = (const float*)d_in[8];
  const float* b2 = (const float*)d_in[9];
  const float* m2 = (const float*)d_in[10];
  const float* v2 = (const float*)d_in[11];
  const float* rw = (const float*)d_in[12];
  float* out = (float*)d_out;

  char* ws = (char*)d_ws;
  u16* cat    = (u16*)(ws);                    // 72,253,440 B
  u16* w2t    = (u16*)(ws + 72253440);         // 23,592,960 B
  u16* pre    = (u16*)(ws + 95846400);         // 47,316,992 B
  u16* w1b    = (u16*)(ws + 143163392);
  u16* cwt    = (u16*)(ws + 143228928);
  float* scale1 = (float*)(ws + 144539648);
  float* shift1 = (float*)(ws + 144539904);
  float* scale2 = (float*)(ws + 144540160);
  float* shift2 = (float*)(ws + 144544256);
  float* cbf    = (float*)(ws + 144548352);

  hipMemsetAsync(cat, 0, 72253440, stream);  // zero spatial padding

  k_prep_small<<<2696, 256, 0, stream>>>(w1, rw, g1, b1, m1, v1, g2, b2, m2, v2,
                                         w1b, cwt, scale1, shift1, scale2, shift2, cbf);
  k_prep_w2<<<1024, 256, 0, stream>>>(w2, w2t);
  k_feat0<<<dim3(12, 32, 64), 256, 0, stream>>>(feat0, cat);
  k_conv1<<<722, 256, 0, stream>>>(feat1, w1b, scale1, shift1, cat);
  k_conv2<<<364, 512, 0, stream>>>(cat, w2t, scale2, shift2, pre);
  k_einsum<<<dim3(5, 181), 256, 0, stream>>>(pre, cwt, cbf, out);
}